// Round 8
// baseline (251.568 us; speedup 1.0000x reference)
//
#include <hip/hip_runtime.h>
#include <hip/hip_bf16.h>

#define IN_CH 128
#define OUT_CH 64
// cnt/pos are padded: one int per 64B cache line (stride 16) to kill
// same-line atomic serialization in the L2 atomic units.
#define PAD 4   // index << 4

// ---------------- degree count (int4-vectorized, line-padded counters) ----------------
__global__ void __launch_bounds__(256) count_kernel(const int* __restrict__ col,
                                                    int* __restrict__ cnt, int E) {
    int t = blockIdx.x * blockDim.x + threadIdx.x;
    int base = t * 4;
    if (base + 3 < E) {
        int4 c = *(const int4*)(col + base);
        atomicAdd(&cnt[c.x << PAD], 1);
        atomicAdd(&cnt[c.y << PAD], 1);
        atomicAdd(&cnt[c.z << PAD], 1);
        atomicAdd(&cnt[c.w << PAD], 1);
    } else {
        for (int i = base; i < E; ++i) atomicAdd(&cnt[col[i] << PAD], 1);
    }
}

// ---------------- 3-phase parallel exclusive scan ----------------
__global__ void __launch_bounds__(256) partial_kernel(const int* __restrict__ cnt,
                                                      int* __restrict__ bsum, int n) {
    __shared__ int red[256];
    int tid = threadIdx.x;
    int i = blockIdx.x * 256 + tid;
    red[tid] = (i < n) ? cnt[i << PAD] : 0;
    __syncthreads();
    for (int d = 128; d > 0; d >>= 1) {
        if (tid < d) red[tid] += red[tid + d];
        __syncthreads();
    }
    if (tid == 0) bsum[blockIdx.x] = red[0];
}

__global__ void __launch_bounds__(256) scansums_kernel(int* __restrict__ bsum, int nb) {
    __shared__ int ps[256];
    int tid = threadIdx.x;
    int v = (tid < nb) ? bsum[tid] : 0;
    ps[tid] = v;
    __syncthreads();
    for (int d = 1; d < 256; d <<= 1) {
        int t = 0;
        if (tid >= d) t = ps[tid - d];
        __syncthreads();
        if (tid >= d) ps[tid] += t;
        __syncthreads();
    }
    if (tid < nb) bsum[tid] = ps[tid] - v;   // exclusive
}

__global__ void __launch_bounds__(256) scanwrite_kernel(const int* __restrict__ cnt,
                                                        const int* __restrict__ bsum,
                                                        int* __restrict__ off,
                                                        int* __restrict__ pos,
                                                        float* __restrict__ dis, int n) {
    __shared__ int ps[256];
    int tid = threadIdx.x;
    int i = blockIdx.x * 256 + tid;
    int c = (i < n) ? cnt[i << PAD] : 0;
    ps[tid] = c;
    __syncthreads();
    for (int d = 1; d < 256; d <<= 1) {
        int t = 0;
        if (tid >= d) t = ps[tid - d];
        __syncthreads();
        if (tid >= d) ps[tid] += t;
        __syncthreads();
    }
    int excl = ps[tid] - c + bsum[blockIdx.x];
    if (i < n) {
        off[i] = excl;
        pos[i << PAD] = excl;
        dis[i] = rsqrtf((float)(c + 1));   // +1 self-loop, matches gcn_norm
        if (i == n - 1) off[n] = excl + c;
    }
}

// ---------------- scatter: CSR build, line-padded position counters ----------------
__global__ void __launch_bounds__(256) scatter_kernel(const int* __restrict__ row,
                                                      const int* __restrict__ col,
                                                      int* __restrict__ pos,
                                                      unsigned short* __restrict__ eidx,
                                                      int E) {
    int t = blockIdx.x * blockDim.x + threadIdx.x;
    int base = t * 2;
    if (base + 1 < E) {
        int2 r = *(const int2*)(row + base);
        int2 c = *(const int2*)(col + base);
        int p0 = atomicAdd(&pos[c.x << PAD], 1);
        eidx[p0] = (unsigned short)r.x;
        int p1 = atomicAdd(&pos[c.y << PAD], 1);
        eidx[p1] = (unsigned short)r.y;
    } else if (base < E) {
        int r = row[base], c = col[base];
        int p = atomicAdd(&pos[c << PAD], 1);
        eidx[p] = (unsigned short)r;
    }
}

// ---------------- z = dis * (X @ W^T) : register-tiled LDS GEMM ----------------
__global__ void __launch_bounds__(256, 2) gemm_kernel(const float* __restrict__ x,
                                                      const float* __restrict__ W,
                                                      const float* __restrict__ dis,
                                                      float* __restrict__ z, int n) {
    __shared__ float Xs[64 * 132];
    __shared__ float Ws[64 * 132];
    int t = threadIdx.x;
    int m0 = blockIdx.x * 64;
#pragma unroll
    for (int r = 0; r < 8; ++r) {               // stage W: 64x128 = 2048 float4
        int f = t + 256 * r;
        int o = f >> 5, kq = f & 31;
        float4 w = ((const float4*)W)[f];
        *(float4*)&Ws[o * 132 + kq * 4] = w;
    }
#pragma unroll
    for (int r = 0; r < 8; ++r) {               // stage X tile (clamped tail)
        int f = t + 256 * r;
        int node = f >> 5, kq = f & 31;
        int gv = min(m0 + node, n - 1);
        float4 xv = ((const float4*)(x + (size_t)gv * IN_CH))[kq];
        *(float4*)&Xs[node * 132 + kq * 4] = xv;
    }
    __syncthreads();
    int tx = t & 15, ty = t >> 4;
    float acc[4][4];
#pragma unroll
    for (int i = 0; i < 4; ++i)
#pragma unroll
        for (int j = 0; j < 4; ++j) acc[i][j] = 0.f;

#pragma unroll 4
    for (int kq = 0; kq < 32; ++kq) {
        float4 xa[4], wb[4];
#pragma unroll
        for (int i = 0; i < 4; ++i) xa[i] = *(const float4*)&Xs[(tx + 16 * i) * 132 + kq * 4];
#pragma unroll
        for (int j = 0; j < 4; ++j) wb[j] = *(const float4*)&Ws[(ty * 4 + j) * 132 + kq * 4];
#pragma unroll
        for (int i = 0; i < 4; ++i)
#pragma unroll
            for (int j = 0; j < 4; ++j) {
                float s = acc[i][j];
                s = fmaf(xa[i].x, wb[j].x, s);
                s = fmaf(xa[i].y, wb[j].y, s);
                s = fmaf(xa[i].z, wb[j].z, s);
                s = fmaf(xa[i].w, wb[j].w, s);
                acc[i][j] = s;
            }
    }
#pragma unroll
    for (int i = 0; i < 4; ++i) {
        int v = m0 + tx + 16 * i;
        if (v < n) {
            float dv = dis[v];
            float4 o4 = make_float4(dv * acc[i][0], dv * acc[i][1],
                                    dv * acc[i][2], dv * acc[i][3]);
            *(float4*)&z[(size_t)v * OUT_CH + ty * 4] = o4;
        }
    }
}

// ---------------- propagation hop: wave per node, 4 edges x float4 per issue ----------------
// t[v] = zin[v] + sum_{edges} zin[row];  MODE 0: out = dis^2 * t (next z)
//                                        MODE 1: out = dis * t + bias (final)
template <int MODE>
__global__ void __launch_bounds__(256) hop_kernel(const float* __restrict__ zin,
                                                  float* __restrict__ out,
                                                  const unsigned short* __restrict__ eidx,
                                                  const int* __restrict__ off,
                                                  const float* __restrict__ dis,
                                                  const float* __restrict__ bias, int n) {
    int v = (int)((blockIdx.x * 256 + threadIdx.x) >> 6);
    if (v >= n) return;
    int lane = threadIdx.x & 63;
    int grp = lane >> 4;       // which edge within a quad
    int sub = lane & 15;       // which float4 chunk of the 64-float row
    int s = off[v], e = off[v + 1];
    float4 acc = make_float4(0.f, 0.f, 0.f, 0.f);
    if (grp == 0) {            // self-loop term (z already carries dis scaling)
        acc = ((const float4*)(zin + (size_t)v * OUT_CH))[sub];
    }
    int i = s + grp;
    bool have = (i < e);
    int r = have ? (int)eidx[i] : 0;
    while (have) {
        int j = i + 4;
        bool hnext = (j < e);
        int rn = hnext ? (int)eidx[j] : 0;   // prefetch next descriptor
        float4 t = ((const float4*)(zin + (size_t)r * OUT_CH))[sub];
        acc.x += t.x; acc.y += t.y; acc.z += t.z; acc.w += t.w;
        r = rn; i = j; have = hnext;
    }
    // reduce the 4 edge slots: lanes {sub, sub+16, sub+32, sub+48}
    acc.x += __shfl_xor(acc.x, 16, 64); acc.x += __shfl_xor(acc.x, 32, 64);
    acc.y += __shfl_xor(acc.y, 16, 64); acc.y += __shfl_xor(acc.y, 32, 64);
    acc.z += __shfl_xor(acc.z, 16, 64); acc.z += __shfl_xor(acc.z, 32, 64);
    acc.w += __shfl_xor(acc.w, 16, 64); acc.w += __shfl_xor(acc.w, 32, 64);
    if (grp == 0) {
        float dv = dis[v];
        float sc = (MODE == 0) ? dv * dv : dv;
        float4 o4 = make_float4(sc * acc.x, sc * acc.y, sc * acc.z, sc * acc.w);
        if (MODE == 1) {
            float4 bb = ((const float4*)bias)[sub];
            o4.x += bb.x; o4.y += bb.y; o4.z += bb.z; o4.w += bb.w;
        }
        ((float4*)(out + (size_t)v * OUT_CH))[sub] = o4;
    }
}

extern "C" void kernel_launch(void* const* d_in, const int* in_sizes, int n_in,
                              void* d_out, int out_size, void* d_ws, size_t ws_size,
                              hipStream_t stream) {
    const float* x = (const float*)d_in[0];
    const int* ei = (const int*)d_in[1];
    const float* W = (const float*)d_in[2];
    const float* b = (const float*)d_in[3];
    int n = in_sizes[0] / IN_CH;   // 50000
    int E = in_sizes[1] / 2;       // 800000
    const int* row = ei;           // edge_index[0] = source
    const int* col = ei + E;       // edge_index[1] = target

    char* ws = (char*)d_ws;
    size_t o = 0;
    auto alloc = [&](size_t bytes) -> void* {
        void* p = ws + o;
        o += (bytes + 255) & ~(size_t)255;
        return p;
    };
    int*            cnt  = (int*)alloc(((size_t)n << PAD) * 4);   // line-padded
    int*            pos  = (int*)alloc(((size_t)n << PAD) * 4);   // line-padded
    int*            off  = (int*)alloc((size_t)(n + 1) * 4);
    float*          dis  = (float*)alloc((size_t)n * 4);
    unsigned short* eidx = (unsigned short*)alloc((size_t)E * 2);
    float*          zA   = (float*)alloc((size_t)n * OUT_CH * 4);
    float*          zB   = (float*)alloc((size_t)n * OUT_CH * 4);
    int*            bsum = (int*)alloc(1024 * 4);

    int nTiles = (n + 255) / 256;  // 196

    hipMemsetAsync(cnt, 0, ((size_t)n << PAD) * 4, stream);
    count_kernel<<<((E + 3) / 4 + 255) / 256, 256, 0, stream>>>(col, cnt, E);
    partial_kernel<<<nTiles, 256, 0, stream>>>(cnt, bsum, n);
    scansums_kernel<<<1, 256, 0, stream>>>(bsum, nTiles);
    scanwrite_kernel<<<nTiles, 256, 0, stream>>>(cnt, bsum, off, pos, dis, n);
    scatter_kernel<<<((E + 1) / 2 + 255) / 256, 256, 0, stream>>>(row, col, pos, eidx, E);
    gemm_kernel<<<(n + 63) / 64, 256, 0, stream>>>(x, W, dis, zA, n);
    int hopBlocks = (n + 3) / 4;   // wave per node
    hop_kernel<0><<<hopBlocks, 256, 0, stream>>>(zA, zB, eidx, off, dis, nullptr, n);
    hop_kernel<1><<<hopBlocks, 256, 0, stream>>>(zB, (float*)d_out, eidx, off, dis, b, n);
}

// Round 9
// 198.665 us; speedup vs baseline: 1.2663x; 1.2663x over previous
//
#include <hip/hip_runtime.h>
#include <hip/hip_bf16.h>

#define IN_CH 128
#define OUT_CH 64
#define NB 240   // edge-chunk blocks for histo/bucket_scatter

// ---------------- K1: per-block 256-bucket histogram of col>>8 ----------------
__global__ void __launch_bounds__(256) histo_kernel(const int* __restrict__ col,
                                                    int* __restrict__ blkcnt,
                                                    int* __restrict__ totals,
                                                    int E, int chunk) {
    __shared__ int h[256];
    int blk = blockIdx.x, tid = threadIdx.x;
    h[tid] = 0;
    __syncthreads();
    int s = blk * chunk, e = min(s + chunk, E);
    for (int i = s + tid; i < e; i += 256)
        atomicAdd(&h[col[i] >> 8], 1);          // LDS atomic
    __syncthreads();
    int v = h[tid];
    blkcnt[blk * 256 + tid] = v;                // coalesced
    if (v) atomicAdd(&totals[tid], v);          // 47k global atomics total
}

// ---------------- K2a: cross-block exclusive scan per bucket ----------------
__global__ void __launch_bounds__(256) scanblk_kernel(int* __restrict__ blkcnt, int nb) {
    __shared__ int ps[256];
    int b = blockIdx.x, tid = threadIdx.x;
    int v = (tid < nb) ? blkcnt[tid * 256 + b] : 0;
    ps[tid] = v;
    __syncthreads();
    for (int d = 1; d < 256; d <<= 1) {
        int t = 0;
        if (tid >= d) t = ps[tid - d];
        __syncthreads();
        if (tid >= d) ps[tid] += t;
        __syncthreads();
    }
    if (tid < nb) blkcnt[tid * 256 + b] = ps[tid] - v;   // exclusive
}

// ---------------- K2b: scan bucket totals -> bucket bases ----------------
__global__ void __launch_bounds__(256) scantot_kernel(const int* __restrict__ totals,
                                                      int* __restrict__ bstart,
                                                      int* __restrict__ off,
                                                      int nbkt, int E, int n) {
    __shared__ int ps[256];
    int tid = threadIdx.x;
    int v = (tid < nbkt) ? totals[tid] : 0;
    ps[tid] = v;
    __syncthreads();
    for (int d = 1; d < 256; d <<= 1) {
        int t = 0;
        if (tid >= d) t = ps[tid - d];
        __syncthreads();
        if (tid >= d) ps[tid] += t;
        __syncthreads();
    }
    if (tid < nbkt) bstart[tid] = ps[tid] - v;
    if (tid == 0) { bstart[nbkt] = E; off[n] = E; }
}

// ---------------- K3: scatter edges into bucket-contiguous tmp ----------------
// LDS cursors -> each (block,bucket) output run is ~68B contiguous; writes
// land in <=2-block-shared lines (~2x tmp writebacks vs 25x before).
__global__ void __launch_bounds__(256) bucket_scatter_kernel(const int* __restrict__ row,
                                                             const int* __restrict__ col,
                                                             const int* __restrict__ blkcnt,
                                                             const int* __restrict__ bstart,
                                                             unsigned int* __restrict__ tmp,
                                                             int E, int chunk, int nbkt) {
    __shared__ int cur[256];
    int blk = blockIdx.x, tid = threadIdx.x;
    cur[tid] = (tid < nbkt) ? bstart[tid] + blkcnt[blk * 256 + tid] : 0;
    __syncthreads();
    int s = blk * chunk, e = min(s + chunk, E);
    for (int i = s + tid; i < e; i += 256) {
        int c = col[i], r = row[i];
        int p = atomicAdd(&cur[c >> 8], 1);     // LDS atomic
        tmp[p] = ((unsigned)(c & 255) << 16) | (unsigned)r;
    }
}

// ---------------- K4: per-bucket counting sort -> off/dis/eidx ----------------
// One block per bucket (256 node ids, ~4k edges). All eidx stores confined to
// this block's ~8KB region -> one L2 assembles lines fully.
__global__ void __launch_bounds__(256) bucket_sort_kernel(const unsigned int* __restrict__ tmp,
                                                          const int* __restrict__ bstart,
                                                          int* __restrict__ off,
                                                          float* __restrict__ dis,
                                                          unsigned short* __restrict__ eidx,
                                                          int n) {
    __shared__ int cntl[256];
    __shared__ int sc[256];
    __shared__ int posl[256];
    int b = blockIdx.x, tid = threadIdx.x;
    int s = bstart[b], e = bstart[b + 1];
    cntl[tid] = 0;
    __syncthreads();
    for (int i = s + tid; i < e; i += 256)
        atomicAdd(&cntl[tmp[i] >> 16], 1);      // LDS atomic
    __syncthreads();
    int c = cntl[tid];
    sc[tid] = c;
    __syncthreads();
    for (int d = 1; d < 256; d <<= 1) {
        int t = 0;
        if (tid >= d) t = sc[tid - d];
        __syncthreads();
        if (tid >= d) sc[tid] += t;
        __syncthreads();
    }
    int excl = sc[tid] - c;
    int gid = (b << 8) + tid;
    if (gid < n) {
        off[gid] = s + excl;
        dis[gid] = rsqrtf((float)(c + 1));      // +1 self-loop (gcn_norm)
    }
    posl[tid] = s + excl;                        // absolute running cursor
    __syncthreads();
    for (int i = s + tid; i < e; i += 256) {
        unsigned int v = tmp[i];
        int p = atomicAdd(&posl[v >> 16], 1);
        eidx[p] = (unsigned short)(v & 0xFFFFu);
    }
}

// ---------------- z = dis * (X @ W^T) : register-tiled LDS GEMM ----------------
__global__ void __launch_bounds__(256, 2) gemm_kernel(const float* __restrict__ x,
                                                      const float* __restrict__ W,
                                                      const float* __restrict__ dis,
                                                      float* __restrict__ z, int n) {
    __shared__ float Xs[64 * 132];
    __shared__ float Ws[64 * 132];
    int t = threadIdx.x;
    int m0 = blockIdx.x * 64;
#pragma unroll
    for (int r = 0; r < 8; ++r) {               // stage W: 64x128 = 2048 float4
        int f = t + 256 * r;
        int o = f >> 5, kq = f & 31;
        float4 w = ((const float4*)W)[f];
        *(float4*)&Ws[o * 132 + kq * 4] = w;
    }
#pragma unroll
    for (int r = 0; r < 8; ++r) {               // stage X tile (clamped tail)
        int f = t + 256 * r;
        int node = f >> 5, kq = f & 31;
        int gv = min(m0 + node, n - 1);
        float4 xv = ((const float4*)(x + (size_t)gv * IN_CH))[kq];
        *(float4*)&Xs[node * 132 + kq * 4] = xv;
    }
    __syncthreads();
    int tx = t & 15, ty = t >> 4;
    float acc[4][4];
#pragma unroll
    for (int i = 0; i < 4; ++i)
#pragma unroll
        for (int j = 0; j < 4; ++j) acc[i][j] = 0.f;

#pragma unroll 4
    for (int kq = 0; kq < 32; ++kq) {
        float4 xa[4], wb[4];
#pragma unroll
        for (int i = 0; i < 4; ++i) xa[i] = *(const float4*)&Xs[(tx + 16 * i) * 132 + kq * 4];
#pragma unroll
        for (int j = 0; j < 4; ++j) wb[j] = *(const float4*)&Ws[(ty * 4 + j) * 132 + kq * 4];
#pragma unroll
        for (int i = 0; i < 4; ++i)
#pragma unroll
            for (int j = 0; j < 4; ++j) {
                float s = acc[i][j];
                s = fmaf(xa[i].x, wb[j].x, s);
                s = fmaf(xa[i].y, wb[j].y, s);
                s = fmaf(xa[i].z, wb[j].z, s);
                s = fmaf(xa[i].w, wb[j].w, s);
                acc[i][j] = s;
            }
    }
#pragma unroll
    for (int i = 0; i < 4; ++i) {
        int v = m0 + tx + 16 * i;
        if (v < n) {
            float dv = dis[v];
            float4 o4 = make_float4(dv * acc[i][0], dv * acc[i][1],
                                    dv * acc[i][2], dv * acc[i][3]);
            *(float4*)&z[(size_t)v * OUT_CH + ty * 4] = o4;
        }
    }
}

// ---------------- propagation hop: wave per node, 4 edges x float4 per issue ----------------
// t[v] = zin[v] + sum_{edges} zin[row];  MODE 0: out = dis^2 * t (next z)
//                                        MODE 1: out = dis * t + bias (final)
template <int MODE>
__global__ void __launch_bounds__(256) hop_kernel(const float* __restrict__ zin,
                                                  float* __restrict__ out,
                                                  const unsigned short* __restrict__ eidx,
                                                  const int* __restrict__ off,
                                                  const float* __restrict__ dis,
                                                  const float* __restrict__ bias, int n) {
    int v = (int)((blockIdx.x * 256 + threadIdx.x) >> 6);
    if (v >= n) return;
    int lane = threadIdx.x & 63;
    int grp = lane >> 4;       // which edge within a quad
    int sub = lane & 15;       // which float4 chunk of the 64-float row
    int s = off[v], e = off[v + 1];
    float4 acc = make_float4(0.f, 0.f, 0.f, 0.f);
    if (grp == 0) {            // self-loop term (z already carries dis scaling)
        acc = ((const float4*)(zin + (size_t)v * OUT_CH))[sub];
    }
    int i = s + grp;
    bool have = (i < e);
    int r = have ? (int)eidx[i] : 0;
    while (have) {
        int j = i + 4;
        bool hnext = (j < e);
        int rn = hnext ? (int)eidx[j] : 0;   // prefetch next descriptor
        float4 t = ((const float4*)(zin + (size_t)r * OUT_CH))[sub];
        acc.x += t.x; acc.y += t.y; acc.z += t.z; acc.w += t.w;
        r = rn; i = j; have = hnext;
    }
    // reduce the 4 edge slots: lanes {sub, sub+16, sub+32, sub+48}
    acc.x += __shfl_xor(acc.x, 16, 64); acc.x += __shfl_xor(acc.x, 32, 64);
    acc.y += __shfl_xor(acc.y, 16, 64); acc.y += __shfl_xor(acc.y, 32, 64);
    acc.z += __shfl_xor(acc.z, 16, 64); acc.z += __shfl_xor(acc.z, 32, 64);
    acc.w += __shfl_xor(acc.w, 16, 64); acc.w += __shfl_xor(acc.w, 32, 64);
    if (grp == 0) {
        float dv = dis[v];
        float sc = (MODE == 0) ? dv * dv : dv;
        float4 o4 = make_float4(sc * acc.x, sc * acc.y, sc * acc.z, sc * acc.w);
        if (MODE == 1) {
            float4 bb = ((const float4*)bias)[sub];
            o4.x += bb.x; o4.y += bb.y; o4.z += bb.z; o4.w += bb.w;
        }
        ((float4*)(out + (size_t)v * OUT_CH))[sub] = o4;
    }
}

extern "C" void kernel_launch(void* const* d_in, const int* in_sizes, int n_in,
                              void* d_out, int out_size, void* d_ws, size_t ws_size,
                              hipStream_t stream) {
    const float* x = (const float*)d_in[0];
    const int* ei = (const int*)d_in[1];
    const float* W = (const float*)d_in[2];
    const float* b = (const float*)d_in[3];
    int n = in_sizes[0] / IN_CH;   // 50000
    int E = in_sizes[1] / 2;       // 800000
    const int* row = ei;           // edge_index[0] = source
    const int* col = ei + E;       // edge_index[1] = target

    char* ws = (char*)d_ws;
    size_t o = 0;
    auto alloc = [&](size_t bytes) -> void* {
        void* p = ws + o;
        o += (bytes + 255) & ~(size_t)255;
        return p;
    };
    int nbkt = (n + 255) >> 8;      // 196
    int chunk = (E + NB - 1) / NB;  // 3334

    int*            blkcnt = (int*)alloc((size_t)NB * 256 * 4);
    int*            totals = (int*)alloc(256 * 4);
    int*            bstart = (int*)alloc((size_t)(nbkt + 1) * 4);
    unsigned int*   tmp    = (unsigned int*)alloc((size_t)E * 4);
    int*            off    = (int*)alloc((size_t)(n + 1) * 4);
    float*          dis    = (float*)alloc((size_t)n * 4);
    unsigned short* eidx   = (unsigned short*)alloc((size_t)E * 2);
    float*          zA     = (float*)alloc((size_t)n * OUT_CH * 4);
    float*          zB     = (float*)alloc((size_t)n * OUT_CH * 4);

    hipMemsetAsync(totals, 0, 256 * 4, stream);
    histo_kernel<<<NB, 256, 0, stream>>>(col, blkcnt, totals, E, chunk);
    scanblk_kernel<<<nbkt, 256, 0, stream>>>(blkcnt, NB);
    scantot_kernel<<<1, 256, 0, stream>>>(totals, bstart, off, nbkt, E, n);
    bucket_scatter_kernel<<<NB, 256, 0, stream>>>(row, col, blkcnt, bstart, tmp, E, chunk, nbkt);
    bucket_sort_kernel<<<nbkt, 256, 0, stream>>>(tmp, bstart, off, dis, eidx, n);
    gemm_kernel<<<(n + 63) / 64, 256, 0, stream>>>(x, W, dis, zA, n);
    int hopBlocks = (n + 3) / 4;   // wave per node
    hop_kernel<0><<<hopBlocks, 256, 0, stream>>>(zA, zB, eidx, off, dis, nullptr, n);
    hop_kernel<1><<<hopBlocks, 256, 0, stream>>>(zB, (float*)d_out, eidx, off, dis, b, n);
}

// Round 10
// 174.255 us; speedup vs baseline: 1.4437x; 1.1401x over previous
//
#include <hip/hip_runtime.h>
#include <hip/hip_bf16.h>
#include <hip/hip_fp16.h>

#define IN_CH 128
#define OUT_CH 64
#define NB 240   // edge-chunk blocks for histo/bucket_scatter

// ---------------- K1: per-block 256-bucket histogram of col>>8 ----------------
__global__ void __launch_bounds__(256) histo_kernel(const int* __restrict__ col,
                                                    int* __restrict__ blkcnt,
                                                    int* __restrict__ totals,
                                                    int E, int chunk) {
    __shared__ int h[256];
    int blk = blockIdx.x, tid = threadIdx.x;
    h[tid] = 0;
    __syncthreads();
    int s = blk * chunk, e = min(s + chunk, E);
    for (int i = s + tid; i < e; i += 256)
        atomicAdd(&h[col[i] >> 8], 1);          // LDS atomic
    __syncthreads();
    int v = h[tid];
    blkcnt[blk * 256 + tid] = v;                // coalesced
    if (v) atomicAdd(&totals[tid], v);          // 47k global atomics total
}

// ---------------- K2: fused cross-block scan (blocks 0..nbkt-1) + bucket-base scan (block nbkt) ----------------
__global__ void __launch_bounds__(256) scan2_kernel(int* __restrict__ blkcnt,
                                                    const int* __restrict__ totals,
                                                    int* __restrict__ bstart,
                                                    int* __restrict__ off,
                                                    int nb, int nbkt, int E, int n) {
    __shared__ int ps[256];
    int tid = threadIdx.x;
    if (blockIdx.x < (unsigned)nbkt) {
        int b = blockIdx.x;
        int v = (tid < nb) ? blkcnt[tid * 256 + b] : 0;
        ps[tid] = v;
        __syncthreads();
        for (int d = 1; d < 256; d <<= 1) {
            int t = 0;
            if (tid >= d) t = ps[tid - d];
            __syncthreads();
            if (tid >= d) ps[tid] += t;
            __syncthreads();
        }
        if (tid < nb) blkcnt[tid * 256 + b] = ps[tid] - v;   // exclusive
    } else {
        int v = (tid < nbkt) ? totals[tid] : 0;
        ps[tid] = v;
        __syncthreads();
        for (int d = 1; d < 256; d <<= 1) {
            int t = 0;
            if (tid >= d) t = ps[tid - d];
            __syncthreads();
            if (tid >= d) ps[tid] += t;
            __syncthreads();
        }
        if (tid < nbkt) bstart[tid] = ps[tid] - v;
        if (tid == 0) { bstart[nbkt] = E; off[n] = E; }
    }
}

// ---------------- K3: scatter edges into bucket-contiguous tmp ----------------
__global__ void __launch_bounds__(256) bucket_scatter_kernel(const int* __restrict__ row,
                                                             const int* __restrict__ col,
                                                             const int* __restrict__ blkcnt,
                                                             const int* __restrict__ bstart,
                                                             unsigned int* __restrict__ tmp,
                                                             int E, int chunk, int nbkt) {
    __shared__ int cur[256];
    int blk = blockIdx.x, tid = threadIdx.x;
    cur[tid] = (tid < nbkt) ? bstart[tid] + blkcnt[blk * 256 + tid] : 0;
    __syncthreads();
    int s = blk * chunk, e = min(s + chunk, E);
    for (int i = s + tid; i < e; i += 256) {
        int c = col[i], r = row[i];
        int p = atomicAdd(&cur[c >> 8], 1);     // LDS atomic
        tmp[p] = ((unsigned)(c & 255) << 16) | (unsigned)r;
    }
}

// ---------------- K4: per-bucket counting sort -> off/dis/eidx ----------------
__global__ void __launch_bounds__(256) bucket_sort_kernel(const unsigned int* __restrict__ tmp,
                                                          const int* __restrict__ bstart,
                                                          int* __restrict__ off,
                                                          float* __restrict__ dis,
                                                          unsigned short* __restrict__ eidx,
                                                          int n) {
    __shared__ int cntl[256];
    __shared__ int sc[256];
    __shared__ int posl[256];
    int b = blockIdx.x, tid = threadIdx.x;
    int s = bstart[b], e = bstart[b + 1];
    cntl[tid] = 0;
    __syncthreads();
    for (int i = s + tid; i < e; i += 256)
        atomicAdd(&cntl[tmp[i] >> 16], 1);      // LDS atomic
    __syncthreads();
    int c = cntl[tid];
    sc[tid] = c;
    __syncthreads();
    for (int d = 1; d < 256; d <<= 1) {
        int t = 0;
        if (tid >= d) t = sc[tid - d];
        __syncthreads();
        if (tid >= d) sc[tid] += t;
        __syncthreads();
    }
    int excl = sc[tid] - c;
    int gid = (b << 8) + tid;
    if (gid < n) {
        off[gid] = s + excl;
        dis[gid] = rsqrtf((float)(c + 1));      // +1 self-loop (gcn_norm)
    }
    posl[tid] = s + excl;                        // absolute running cursor
    __syncthreads();
    for (int i = s + tid; i < e; i += 256) {
        unsigned int v = tmp[i];
        int p = atomicAdd(&posl[v >> 16], 1);
        eidx[p] = (unsigned short)(v & 0xFFFFu);
    }
}

// ---------------- z = fp16( dis * (X @ W^T) ) : register-tiled LDS GEMM ----------------
__global__ void __launch_bounds__(256, 2) gemm_kernel(const float* __restrict__ x,
                                                      const float* __restrict__ W,
                                                      const float* __restrict__ dis,
                                                      __half* __restrict__ z, int n) {
    __shared__ float Xs[64 * 132];
    __shared__ float Ws[64 * 132];
    int t = threadIdx.x;
    int m0 = blockIdx.x * 64;
#pragma unroll
    for (int r = 0; r < 8; ++r) {               // stage W: 64x128 = 2048 float4
        int f = t + 256 * r;
        int o = f >> 5, kq = f & 31;
        float4 w = ((const float4*)W)[f];
        *(float4*)&Ws[o * 132 + kq * 4] = w;
    }
#pragma unroll
    for (int r = 0; r < 8; ++r) {               // stage X tile (clamped tail)
        int f = t + 256 * r;
        int node = f >> 5, kq = f & 31;
        int gv = min(m0 + node, n - 1);
        float4 xv = ((const float4*)(x + (size_t)gv * IN_CH))[kq];
        *(float4*)&Xs[node * 132 + kq * 4] = xv;
    }
    __syncthreads();
    int tx = t & 15, ty = t >> 4;
    float acc[4][4];
#pragma unroll
    for (int i = 0; i < 4; ++i)
#pragma unroll
        for (int j = 0; j < 4; ++j) acc[i][j] = 0.f;

#pragma unroll 4
    for (int kq = 0; kq < 32; ++kq) {
        float4 xa[4], wb[4];
#pragma unroll
        for (int i = 0; i < 4; ++i) xa[i] = *(const float4*)&Xs[(tx + 16 * i) * 132 + kq * 4];
#pragma unroll
        for (int j = 0; j < 4; ++j) wb[j] = *(const float4*)&Ws[(ty * 4 + j) * 132 + kq * 4];
#pragma unroll
        for (int i = 0; i < 4; ++i)
#pragma unroll
            for (int j = 0; j < 4; ++j) {
                float s = acc[i][j];
                s = fmaf(xa[i].x, wb[j].x, s);
                s = fmaf(xa[i].y, wb[j].y, s);
                s = fmaf(xa[i].z, wb[j].z, s);
                s = fmaf(xa[i].w, wb[j].w, s);
                acc[i][j] = s;
            }
    }
#pragma unroll
    for (int i = 0; i < 4; ++i) {
        int v = m0 + tx + 16 * i;
        if (v < n) {
            float dv = dis[v];
            union { __half2 h[2]; float2 f; } u;
            u.h[0] = __floats2half2_rn(dv * acc[i][0], dv * acc[i][1]);
            u.h[1] = __floats2half2_rn(dv * acc[i][2], dv * acc[i][3]);
            *(float2*)&z[(size_t)v * OUT_CH + ty * 4] = u.f;   // 8B aligned
        }
    }
}

// ---------------- propagation hop: wave per node, 8 fp16 edges x 16B per issue ----------------
// t[v] = zin[v] + sum_{edges} zin[row]; rows are 64 halves = 128B.
// lane = grp*8+sub: grp in [0,8) = edge slot, sub in [0,8) = 16B (8-half) chunk.
// MODE 0: out(half) = dis^2 * t (next z);  MODE 1: out(float) = dis * t + bias.
template <int MODE>
__global__ void __launch_bounds__(256) hop_kernel(const __half* __restrict__ zin,
                                                  void* __restrict__ out,
                                                  const unsigned short* __restrict__ eidx,
                                                  const int* __restrict__ off,
                                                  const float* __restrict__ dis,
                                                  const float* __restrict__ bias, int n) {
    int v = (int)((blockIdx.x * 256 + threadIdx.x) >> 6);
    if (v >= n) return;
    int lane = threadIdx.x & 63;
    int grp = lane >> 3;       // edge slot in the octet
    int sub = lane & 7;        // 16B chunk of the 128B row
    int s = off[v], e = off[v + 1];
    float a0 = 0.f, a1 = 0.f, a2 = 0.f, a3 = 0.f;
    float a4 = 0.f, a5 = 0.f, a6 = 0.f, a7 = 0.f;
    if (grp == 0) {            // self-loop term (z already carries dis scaling)
        float4 raw = ((const float4*)(zin + (size_t)v * OUT_CH))[sub];
        const __half2* h2 = (const __half2*)&raw;
        float2 f0 = __half22float2(h2[0]), f1 = __half22float2(h2[1]);
        float2 f2 = __half22float2(h2[2]), f3 = __half22float2(h2[3]);
        a0 = f0.x; a1 = f0.y; a2 = f1.x; a3 = f1.y;
        a4 = f2.x; a5 = f2.y; a6 = f3.x; a7 = f3.y;
    }
    int i = s + grp;
    bool have = (i < e);
    int r = have ? (int)eidx[i] : 0;
    while (have) {
        int j = i + 8;
        bool hnext = (j < e);
        int rn = hnext ? (int)eidx[j] : 0;   // prefetch next descriptor
        float4 raw = ((const float4*)(zin + (size_t)r * OUT_CH))[sub];
        const __half2* h2 = (const __half2*)&raw;
        float2 f0 = __half22float2(h2[0]), f1 = __half22float2(h2[1]);
        float2 f2 = __half22float2(h2[2]), f3 = __half22float2(h2[3]);
        a0 += f0.x; a1 += f0.y; a2 += f1.x; a3 += f1.y;
        a4 += f2.x; a5 += f2.y; a6 += f3.x; a7 += f3.y;
        r = rn; i = j; have = hnext;
    }
    // reduce the 8 edge slots (lanes differing in bits 3..5)
#pragma unroll
    for (int m = 8; m <= 32; m <<= 1) {
        a0 += __shfl_xor(a0, m, 64); a1 += __shfl_xor(a1, m, 64);
        a2 += __shfl_xor(a2, m, 64); a3 += __shfl_xor(a3, m, 64);
        a4 += __shfl_xor(a4, m, 64); a5 += __shfl_xor(a5, m, 64);
        a6 += __shfl_xor(a6, m, 64); a7 += __shfl_xor(a7, m, 64);
    }
    if (grp == 0) {
        float dv = dis[v];
        if (MODE == 0) {
            float sc = dv * dv;
            union { __half2 h[4]; float4 f; } u;
            u.h[0] = __floats2half2_rn(sc * a0, sc * a1);
            u.h[1] = __floats2half2_rn(sc * a2, sc * a3);
            u.h[2] = __floats2half2_rn(sc * a4, sc * a5);
            u.h[3] = __floats2half2_rn(sc * a6, sc * a7);
            ((float4*)((__half*)out + (size_t)v * OUT_CH))[sub] = u.f;
        } else {
            const float4* bp = (const float4*)(bias + sub * 8);
            float4 b0 = bp[0], b1 = bp[1];
            float* op = (float*)out + (size_t)v * OUT_CH + sub * 8;
            *(float4*)op = make_float4(fmaf(dv, a0, b0.x), fmaf(dv, a1, b0.y),
                                       fmaf(dv, a2, b0.z), fmaf(dv, a3, b0.w));
            *(float4*)(op + 4) = make_float4(fmaf(dv, a4, b1.x), fmaf(dv, a5, b1.y),
                                             fmaf(dv, a6, b1.z), fmaf(dv, a7, b1.w));
        }
    }
}

extern "C" void kernel_launch(void* const* d_in, const int* in_sizes, int n_in,
                              void* d_out, int out_size, void* d_ws, size_t ws_size,
                              hipStream_t stream) {
    const float* x = (const float*)d_in[0];
    const int* ei = (const int*)d_in[1];
    const float* W = (const float*)d_in[2];
    const float* b = (const float*)d_in[3];
    int n = in_sizes[0] / IN_CH;   // 50000
    int E = in_sizes[1] / 2;       // 800000
    const int* row = ei;           // edge_index[0] = source
    const int* col = ei + E;       // edge_index[1] = target

    char* ws = (char*)d_ws;
    size_t o = 0;
    auto alloc = [&](size_t bytes) -> void* {
        void* p = ws + o;
        o += (bytes + 255) & ~(size_t)255;
        return p;
    };
    int nbkt = (n + 255) >> 8;      // 196
    int chunk = (E + NB - 1) / NB;  // 3334

    int*            blkcnt = (int*)alloc((size_t)NB * 256 * 4);
    int*            totals = (int*)alloc(256 * 4);
    int*            bstart = (int*)alloc((size_t)(nbkt + 1) * 4);
    unsigned int*   tmp    = (unsigned int*)alloc((size_t)E * 4);
    int*            off    = (int*)alloc((size_t)(n + 1) * 4);
    float*          dis    = (float*)alloc((size_t)n * 4);
    unsigned short* eidx   = (unsigned short*)alloc((size_t)E * 2);
    __half*         zA     = (__half*)alloc((size_t)n * OUT_CH * 2);
    __half*         zB     = (__half*)alloc((size_t)n * OUT_CH * 2);

    hipMemsetAsync(totals, 0, 256 * 4, stream);
    histo_kernel<<<NB, 256, 0, stream>>>(col, blkcnt, totals, E, chunk);
    scan2_kernel<<<nbkt + 1, 256, 0, stream>>>(blkcnt, totals, bstart, off, NB, nbkt, E, n);
    bucket_scatter_kernel<<<NB, 256, 0, stream>>>(row, col, blkcnt, bstart, tmp, E, chunk, nbkt);
    bucket_sort_kernel<<<nbkt, 256, 0, stream>>>(tmp, bstart, off, dis, eidx, n);
    gemm_kernel<<<(n + 63) / 64, 256, 0, stream>>>(x, W, dis, zA, n);
    int hopBlocks = (n + 3) / 4;   // wave per node
    hop_kernel<0><<<hopBlocks, 256, 0, stream>>>(zA, zB, eidx, off, dis, nullptr, n);
    hop_kernel<1><<<hopBlocks, 256, 0, stream>>>(zB, d_out, eidx, off, dis, b, n);
}

// Round 11
// 167.901 us; speedup vs baseline: 1.4983x; 1.0378x over previous
//
#include <hip/hip_runtime.h>
#include <hip/hip_bf16.h>
#include <hip/hip_fp16.h>

#define IN_CH 128
#define OUT_CH 64
#define NB 512   // edge-chunk blocks for histo/bucket_scatter (2 blocks/CU)

// ---------------- K1: per-block 256-bucket histogram of col>>8 ----------------
__global__ void __launch_bounds__(512) histo_kernel(const int* __restrict__ col,
                                                    int* __restrict__ blkcnt,
                                                    int E, int chunk) {
    __shared__ int h[256];
    int blk = blockIdx.x, tid = threadIdx.x;
    if (tid < 256) h[tid] = 0;
    __syncthreads();
    int s = blk * chunk, e = min(s + chunk, E);
    for (int i = s + tid; i < e; i += 512)
        atomicAdd(&h[col[i] >> 8], 1);          // LDS atomic
    __syncthreads();
    if (tid < 256) blkcnt[blk * 256 + tid] = h[tid];   // coalesced
}

// ---------------- K2: per-bucket exclusive scan over NB block-counts (in place) ----------------
// Also emits totals[b] (bucket size). One block per bucket; 2 values/thread.
__global__ void __launch_bounds__(256) scanblk_kernel(int* __restrict__ blkcnt,
                                                      int* __restrict__ totals) {
    __shared__ int ps[256];
    int b = blockIdx.x, tid = threadIdx.x;
    int i0 = (2 * tid) * 256 + b, i1 = (2 * tid + 1) * 256 + b;
    int a0 = blkcnt[i0], a1 = blkcnt[i1];
    int lsum = a0 + a1;
    ps[tid] = lsum;
    __syncthreads();
    for (int d = 1; d < 256; d <<= 1) {
        int t = 0;
        if (tid >= d) t = ps[tid - d];
        __syncthreads();
        if (tid >= d) ps[tid] += t;
        __syncthreads();
    }
    int excl = ps[tid] - lsum;
    blkcnt[i0] = excl;
    blkcnt[i1] = excl + a0;
    if (tid == 255) totals[b] = excl + lsum;
}

// ---------------- K3: scatter edges into bucket-contiguous tmp ----------------
// Each block recomputes the 196-entry bucket-base scan from totals (cheap),
// then uses LDS cursors; output runs are contiguous -> low write inflation.
__global__ void __launch_bounds__(512) bucket_scatter_kernel(const int* __restrict__ row,
                                                             const int* __restrict__ col,
                                                             const int* __restrict__ blkcnt,
                                                             const int* __restrict__ totals,
                                                             unsigned int* __restrict__ tmp,
                                                             int E, int chunk, int nbkt) {
    __shared__ int ps[256];
    __shared__ int cur[256];
    int blk = blockIdx.x, tid = threadIdx.x;
    int v = 0;
    if (tid < 256) { v = (tid < nbkt) ? totals[tid] : 0; ps[tid] = v; }
    __syncthreads();
    for (int d = 1; d < 256; d <<= 1) {
        int t = 0;
        if (tid < 256 && tid >= d) t = ps[tid - d];
        __syncthreads();
        if (tid < 256 && tid >= d) ps[tid] += t;
        __syncthreads();
    }
    if (tid < 256) cur[tid] = (ps[tid] - v) + blkcnt[blk * 256 + tid];
    __syncthreads();
    int s = blk * chunk, e = min(s + chunk, E);
    for (int i = s + tid; i < e; i += 512) {
        int c = col[i], r = row[i];
        int p = atomicAdd(&cur[c >> 8], 1);     // LDS atomic
        tmp[p] = ((unsigned)(c & 255) << 16) | (unsigned)r;
    }
}

// ---------------- K4: per-bucket counting sort -> off/dis/eidx ----------------
__global__ void __launch_bounds__(512) bucket_sort_kernel(const unsigned int* __restrict__ tmp,
                                                          const int* __restrict__ totals,
                                                          int* __restrict__ off,
                                                          float* __restrict__ dis,
                                                          unsigned short* __restrict__ eidx,
                                                          int nbkt, int E, int n) {
    __shared__ int bs[256];
    __shared__ int cntl[256];
    __shared__ int sc[256];
    __shared__ int posl[256];
    int b = blockIdx.x, tid = threadIdx.x;
    int v = 0;
    if (tid < 256) { v = (tid < nbkt) ? totals[tid] : 0; bs[tid] = v; }
    __syncthreads();
    for (int d = 1; d < 256; d <<= 1) {
        int t = 0;
        if (tid < 256 && tid >= d) t = bs[tid - d];
        __syncthreads();
        if (tid < 256 && tid >= d) bs[tid] += t;
        __syncthreads();
    }
    if (tid < 256) bs[tid] -= v;                 // exclusive bucket bases
    if (tid < 256) cntl[tid] = 0;
    __syncthreads();
    int s = bs[b];
    int e = s + ((b < nbkt) ? totals[b] : 0);
    for (int i = s + tid; i < e; i += 512)
        atomicAdd(&cntl[tmp[i] >> 16], 1);       // LDS atomic
    __syncthreads();
    int c = 0, excl = 0;
    if (tid < 256) { c = cntl[tid]; sc[tid] = c; }
    __syncthreads();
    for (int d = 1; d < 256; d <<= 1) {
        int t = 0;
        if (tid < 256 && tid >= d) t = sc[tid - d];
        __syncthreads();
        if (tid < 256 && tid >= d) sc[tid] += t;
        __syncthreads();
    }
    if (tid < 256) {
        excl = sc[tid] - c;
        int gid = (b << 8) + tid;
        if (gid < n) {
            off[gid] = s + excl;
            dis[gid] = rsqrtf((float)(c + 1));   // +1 self-loop (gcn_norm)
        }
        posl[tid] = s + excl;                    // absolute running cursor
    }
    if (b == 0 && tid == 0) off[n] = E;
    __syncthreads();
    for (int i = s + tid; i < e; i += 512) {
        unsigned int w = tmp[i];
        int p = atomicAdd(&posl[w >> 16], 1);
        eidx[p] = (unsigned short)(w & 0xFFFFu);
    }
}

// ---------------- z = fp16( dis * (X @ W^T) ) : register-tiled LDS GEMM ----------------
__global__ void __launch_bounds__(256, 2) gemm_kernel(const float* __restrict__ x,
                                                      const float* __restrict__ W,
                                                      const float* __restrict__ dis,
                                                      __half* __restrict__ z, int n) {
    __shared__ float Xs[64 * 132];
    __shared__ float Ws[64 * 132];
    int t = threadIdx.x;
    int m0 = blockIdx.x * 64;
#pragma unroll
    for (int r = 0; r < 8; ++r) {               // stage W: 64x128 = 2048 float4
        int f = t + 256 * r;
        int o = f >> 5, kq = f & 31;
        float4 w = ((const float4*)W)[f];
        *(float4*)&Ws[o * 132 + kq * 4] = w;
    }
#pragma unroll
    for (int r = 0; r < 8; ++r) {               // stage X tile (clamped tail)
        int f = t + 256 * r;
        int node = f >> 5, kq = f & 31;
        int gv = min(m0 + node, n - 1);
        float4 xv = ((const float4*)(x + (size_t)gv * IN_CH))[kq];
        *(float4*)&Xs[node * 132 + kq * 4] = xv;
    }
    __syncthreads();
    int tx = t & 15, ty = t >> 4;
    float acc[4][4];
#pragma unroll
    for (int i = 0; i < 4; ++i)
#pragma unroll
        for (int j = 0; j < 4; ++j) acc[i][j] = 0.f;

#pragma unroll 4
    for (int kq = 0; kq < 32; ++kq) {
        float4 xa[4], wb[4];
#pragma unroll
        for (int i = 0; i < 4; ++i) xa[i] = *(const float4*)&Xs[(tx + 16 * i) * 132 + kq * 4];
#pragma unroll
        for (int j = 0; j < 4; ++j) wb[j] = *(const float4*)&Ws[(ty * 4 + j) * 132 + kq * 4];
#pragma unroll
        for (int i = 0; i < 4; ++i)
#pragma unroll
            for (int j = 0; j < 4; ++j) {
                float s = acc[i][j];
                s = fmaf(xa[i].x, wb[j].x, s);
                s = fmaf(xa[i].y, wb[j].y, s);
                s = fmaf(xa[i].z, wb[j].z, s);
                s = fmaf(xa[i].w, wb[j].w, s);
                acc[i][j] = s;
            }
    }
#pragma unroll
    for (int i = 0; i < 4; ++i) {
        int v = m0 + tx + 16 * i;
        if (v < n) {
            float dv = dis[v];
            union { __half2 h[2]; float2 f; } u;
            u.h[0] = __floats2half2_rn(dv * acc[i][0], dv * acc[i][1]);
            u.h[1] = __floats2half2_rn(dv * acc[i][2], dv * acc[i][3]);
            *(float2*)&z[(size_t)v * OUT_CH + ty * 4] = u.f;   // 8B aligned
        }
    }
}

// ---------------- propagation hop: wave per node, 8 fp16 edges x 16B per issue ----------------
// t[v] = zin[v] + sum_{edges} zin[row]; rows are 64 halves = 128B.
// MODE 0: out(half) = dis^2 * t (next z);  MODE 1: out(float) = dis * t + bias.
template <int MODE>
__global__ void __launch_bounds__(256) hop_kernel(const __half* __restrict__ zin,
                                                  void* __restrict__ out,
                                                  const unsigned short* __restrict__ eidx,
                                                  const int* __restrict__ off,
                                                  const float* __restrict__ dis,
                                                  const float* __restrict__ bias, int n) {
    int v = (int)((blockIdx.x * 256 + threadIdx.x) >> 6);
    if (v >= n) return;
    int lane = threadIdx.x & 63;
    int grp = lane >> 3;       // edge slot in the octet
    int sub = lane & 7;        // 16B chunk of the 128B row
    int s = off[v], e = off[v + 1];
    float a0 = 0.f, a1 = 0.f, a2 = 0.f, a3 = 0.f;
    float a4 = 0.f, a5 = 0.f, a6 = 0.f, a7 = 0.f;
    if (grp == 0) {            // self-loop term (z already carries dis scaling)
        float4 raw = ((const float4*)(zin + (size_t)v * OUT_CH))[sub];
        const __half2* h2 = (const __half2*)&raw;
        float2 f0 = __half22float2(h2[0]), f1 = __half22float2(h2[1]);
        float2 f2 = __half22float2(h2[2]), f3 = __half22float2(h2[3]);
        a0 = f0.x; a1 = f0.y; a2 = f1.x; a3 = f1.y;
        a4 = f2.x; a5 = f2.y; a6 = f3.x; a7 = f3.y;
    }
    int i = s + grp;
    bool have = (i < e);
    int r = have ? (int)eidx[i] : 0;
    while (have) {
        int j = i + 8;
        bool hnext = (j < e);
        int rn = hnext ? (int)eidx[j] : 0;   // prefetch next descriptor
        float4 raw = ((const float4*)(zin + (size_t)r * OUT_CH))[sub];
        const __half2* h2 = (const __half2*)&raw;
        float2 f0 = __half22float2(h2[0]), f1 = __half22float2(h2[1]);
        float2 f2 = __half22float2(h2[2]), f3 = __half22float2(h2[3]);
        a0 += f0.x; a1 += f0.y; a2 += f1.x; a3 += f1.y;
        a4 += f2.x; a5 += f2.y; a6 += f3.x; a7 += f3.y;
        r = rn; i = j; have = hnext;
    }
    // reduce the 8 edge slots (lanes differing in bits 3..5)
#pragma unroll
    for (int m = 8; m <= 32; m <<= 1) {
        a0 += __shfl_xor(a0, m, 64); a1 += __shfl_xor(a1, m, 64);
        a2 += __shfl_xor(a2, m, 64); a3 += __shfl_xor(a3, m, 64);
        a4 += __shfl_xor(a4, m, 64); a5 += __shfl_xor(a5, m, 64);
        a6 += __shfl_xor(a6, m, 64); a7 += __shfl_xor(a7, m, 64);
    }
    if (grp == 0) {
        float dv = dis[v];
        if (MODE == 0) {
            float sc = dv * dv;
            union { __half2 h[4]; float4 f; } u;
            u.h[0] = __floats2half2_rn(sc * a0, sc * a1);
            u.h[1] = __floats2half2_rn(sc * a2, sc * a3);
            u.h[2] = __floats2half2_rn(sc * a4, sc * a5);
            u.h[3] = __floats2half2_rn(sc * a6, sc * a7);
            ((float4*)((__half*)out + (size_t)v * OUT_CH))[sub] = u.f;
        } else {
            const float4* bp = (const float4*)(bias + sub * 8);
            float4 b0 = bp[0], b1 = bp[1];
            float* op = (float*)out + (size_t)v * OUT_CH + sub * 8;
            *(float4*)op = make_float4(fmaf(dv, a0, b0.x), fmaf(dv, a1, b0.y),
                                       fmaf(dv, a2, b0.z), fmaf(dv, a3, b0.w));
            *(float4*)(op + 4) = make_float4(fmaf(dv, a4, b1.x), fmaf(dv, a5, b1.y),
                                             fmaf(dv, a6, b1.z), fmaf(dv, a7, b1.w));
        }
    }
}

extern "C" void kernel_launch(void* const* d_in, const int* in_sizes, int n_in,
                              void* d_out, int out_size, void* d_ws, size_t ws_size,
                              hipStream_t stream) {
    const float* x = (const float*)d_in[0];
    const int* ei = (const int*)d_in[1];
    const float* W = (const float*)d_in[2];
    const float* b = (const float*)d_in[3];
    int n = in_sizes[0] / IN_CH;   // 50000
    int E = in_sizes[1] / 2;       // 800000
    const int* row = ei;           // edge_index[0] = source
    const int* col = ei + E;       // edge_index[1] = target

    char* ws = (char*)d_ws;
    size_t o = 0;
    auto alloc = [&](size_t bytes) -> void* {
        void* p = ws + o;
        o += (bytes + 255) & ~(size_t)255;
        return p;
    };
    int nbkt = (n + 255) >> 8;      // 196
    int chunk = (E + NB - 1) / NB;  // 1563

    int*            blkcnt = (int*)alloc((size_t)NB * 256 * 4);
    int*            totals = (int*)alloc(256 * 4);
    unsigned int*   tmp    = (unsigned int*)alloc((size_t)E * 4);
    int*            off    = (int*)alloc((size_t)(n + 1) * 4);
    float*          dis    = (float*)alloc((size_t)n * 4);
    unsigned short* eidx   = (unsigned short*)alloc((size_t)E * 2);
    __half*         zA     = (__half*)alloc((size_t)n * OUT_CH * 2);
    __half*         zB     = (__half*)alloc((size_t)n * OUT_CH * 2);

    histo_kernel<<<NB, 512, 0, stream>>>(col, blkcnt, E, chunk);
    scanblk_kernel<<<nbkt, 256, 0, stream>>>(blkcnt, totals);
    bucket_scatter_kernel<<<NB, 512, 0, stream>>>(row, col, blkcnt, totals, tmp, E, chunk, nbkt);
    bucket_sort_kernel<<<nbkt, 512, 0, stream>>>(tmp, totals, off, dis, eidx, nbkt, E, n);
    gemm_kernel<<<(n + 63) / 64, 256, 0, stream>>>(x, W, dis, zA, n);
    int hopBlocks = (n + 3) / 4;   // wave per node
    hop_kernel<0><<<hopBlocks, 256, 0, stream>>>(zA, zB, eidx, off, dis, nullptr, n);
    hop_kernel<1><<<hopBlocks, 256, 0, stream>>>(zB, d_out, eidx, off, dis, b, n);
}